// Round 6
// baseline (164.051 us; speedup 1.0000x reference)
//
#include <hip/hip_runtime.h>
#include <hip/hip_cooperative_groups.h>

namespace cg = cooperative_groups;

#define NB 4
#define NN 512
#define NF 64
#define NEG_SLOPE 0.2f
#define LN_EPS 1e-5f
#define WP 66   // padded LDS row stride (words): bank = (2*lane + c) % 32 -> 2-way only (free)

__device__ __forceinline__ float wave_sum(float v){
  #pragma unroll
  for (int d = 32; d; d >>= 1) v += __shfl_xor(v, d, 64);
  return v;
}
__device__ __forceinline__ float wave_max(float v){
  #pragma unroll
  for (int d = 32; d; d >>= 1) v = fmaxf(v, __shfl_xor(v, d, 64));
  return v;
}
__device__ __forceinline__ unsigned int rnd_bf_hi(float f){
  union { float f; unsigned int i; } v; v.f = f;
  return (v.i + 0x7fffu + ((v.i >> 16) & 1u)) & 0xffff0000u;
}

// ws layout (words):
//   r   [NN]              adj row-sums (f32)
//   evh [NB*NN*NF]        packed uint32: hi16 = bf16(h), lo16 = bf16(exp(-Vh))
//   eU  [NB*NN*NF]        exp(-Uh) (f32)
//   li  [NB*NN]           h . a_i
//   lj  [NB*NN]           h . a_j

// Single cooperative kernel, 512 blocks x 256 threads (3 blocks/CU co-resident
// at 52.8 KB LDS -> 512-block cooperative launch is valid).
// Phase A (= old k_setup): block g handles rows g*4+w and adj row-sum j=g.
// grid.sync()
// Phase B (= old k_main): block g -> b = g>>7, i0 = (g&127)*4.
extern "C" __global__ __launch_bounds__(256)
void k_fused(const float* __restrict__ x, const float* __restrict__ adj,
             const float* __restrict__ Ww, const float* __restrict__ Wb,
             const float* __restrict__ Uw, const float* __restrict__ Ub,
             const float* __restrict__ Vw, const float* __restrict__ Vb,
             const float* __restrict__ attw, const float* __restrict__ attb_p,
             const float* __restrict__ lng, const float* __restrict__ lnb,
             float* __restrict__ ws, float* __restrict__ out)
{
  float* r            = ws;
  unsigned int* evh   = (unsigned int*)(ws + NN);
  float* eU           = ws + NN + NB*NN*NF;
  float* li           = eU + NB*NN*NF;
  float* lj           = li + NB*NN;

  __shared__ union SM {
    struct { float w[3*64*WP]; float xx[4][NF]; float h[4][NF]; float red[4]; } a;
    struct { float c[NN][4]; float part[4][4][NF]; } b;
  } sm;

  const int tid  = threadIdx.x;
  const int w    = tid >> 6;
  const int lane = tid & 63;       // = feature f
  const int g    = blockIdx.x;

  // ================= Phase A: setup =================
  {
    const int row = g*4 + w;       // b*NN + n

    // stage weights coalesced: 3 x 4096 floats as float4
    const float4* srcs[3] = { (const float4*)Ww, (const float4*)Uw, (const float4*)Vw };
    #pragma unroll
    for (int m = 0; m < 3; m++){
      const float4* src = srcs[m];
      #pragma unroll
      for (int k = 0; k < 4; k++){
        int idx4 = tid + k*256;          // 1024 float4 per matrix
        float4 v = src[idx4];
        int e = idx4 * 4;
        int f = e >> 6, c = e & 63;
        float* dst = &sm.a.w[m*64*WP + f*WP + c];
        dst[0] = v.x; dst[1] = v.y; dst[2] = v.z; dst[3] = v.w;
      }
    }
    sm.a.xx[w][lane] = x[row*NF + lane];
    __syncthreads();

    // h = x @ Ww^T + Wb (lane = f)
    float hv = Wb[lane];
    {
      const float* wr = &sm.a.w[0*64*WP + lane*WP];
      #pragma unroll
      for (int c = 0; c < NF; c += 2){
        float2 xb = *(const float2*)&sm.a.xx[w][c];   // LDS broadcast
        float2 wv = *(const float2*)&wr[c];           // 2-way aliased (free)
        hv = fmaf(xb.x, wv.x, hv);
        hv = fmaf(xb.y, wv.y, hv);
      }
    }
    sm.a.h[w][lane] = hv;
    __syncthreads();

    // Uh, Vh GEMVs
    float uh = Ub[lane];
    float vh = Vb[lane];
    {
      const float* ur = &sm.a.w[1*64*WP + lane*WP];
      const float* vr = &sm.a.w[2*64*WP + lane*WP];
      #pragma unroll
      for (int c = 0; c < NF; c += 2){
        float2 hb = *(const float2*)&sm.a.h[w][c];
        float2 uv = *(const float2*)&ur[c];
        float2 vv = *(const float2*)&vr[c];
        uh = fmaf(hb.x, uv.x, uh); uh = fmaf(hb.y, uv.y, uh);
        vh = fmaf(hb.x, vv.x, vh); vh = fmaf(hb.y, vv.y, vh);
      }
    }

    float ev = __expf(-vh);
    float eu = __expf(-uh);
    evh[row*NF + lane] = rnd_bf_hi(hv) | (rnd_bf_hi(ev) >> 16);
    eU[row*NF + lane] = eu;

    float pi = wave_sum(hv * attw[lane]);
    float pj = wave_sum(hv * attw[NF + lane]);
    if (lane == 0){ li[row] = pi; lj[row] = pj; }

    // adj row-sum for j = g (coalesced float2, block reduce)
    {
      const float2* a2 = (const float2*)(adj + g*NN);
      float2 a = a2[tid];
      float s = wave_sum(a.x + a.y);
      if (lane == 0) sm.a.red[w] = s;
      __syncthreads();
      if (tid == 0) r[g] = sm.a.red[0] + sm.a.red[1] + sm.a.red[2] + sm.a.red[3];
    }
  }

  cg::this_grid().sync();

  // ================= Phase B: main contraction =================
  {
    const int b  = g >> 7;
    const int i0 = (g & 127) * 4;
    const int i  = i0 + w;

    const float attb = attb_p[0];
    const float li_s = li[b*NN + i];

    float lv[8];
    float m = -1e30f;
    #pragma unroll
    for (int t = 0; t < 8; t++){
      int j = lane + 64*t;
      float l = li_s + lj[b*NN + j] + attb;
      l = (l > 0.f) ? l : NEG_SLOPE*l;
      lv[t] = l;
      m = fmaxf(m, l);
    }
    m = wave_max(m);
    float S = 0.f;
    #pragma unroll
    for (int t = 0; t < 8; t++){ lv[t] = __expf(lv[t] - m); S += lv[t]; }
    S = wave_sum(S);
    float inv = __builtin_amdgcn_rcpf(S);
    #pragma unroll
    for (int t = 0; t < 8; t++){
      int j = lane + 64*t;
      sm.b.c[j][w] = lv[t]*inv*r[j];
    }

    const float eu0 = eU[(b*NN + i0 + 0)*NF + lane];
    const float eu1 = eU[(b*NN + i0 + 1)*NF + lane];
    const float eu2 = eU[(b*NN + i0 + 2)*NF + lane];
    const float eu3 = eU[(b*NN + i0 + 3)*NF + lane];

    __syncthreads();

    const unsigned int* evhb = evh + (size_t)(b*NN)*NF;
    float a0 = 0.f, a1 = 0.f, a2 = 0.f, a3 = 0.f;
    const int j0 = w*128;
    #pragma unroll 8
    for (int jj = 0; jj < 128; jj++){
      int j = j0 + jj;
      unsigned int u = evhb[j*NF + lane];         // coalesced dword, L2-resident
      union { unsigned int i; float f; } hh, ee;
      hh.i = u & 0xffff0000u;                     // bf16(h)
      ee.i = u << 16;                             // bf16(eV)
      float4 c4 = *(const float4*)&sm.b.c[j][0];  // LDS broadcast
      float q0 = fmaf(eu0, ee.f, 1.0f);
      float q1 = fmaf(eu1, ee.f, 1.0f);
      float q2 = fmaf(eu2, ee.f, 1.0f);
      float q3 = fmaf(eu3, ee.f, 1.0f);
      a0 = fmaf(c4.x, hh.f * __builtin_amdgcn_rcpf(q0), a0);
      a1 = fmaf(c4.y, hh.f * __builtin_amdgcn_rcpf(q1), a1);
      a2 = fmaf(c4.z, hh.f * __builtin_amdgcn_rcpf(q2), a2);
      a3 = fmaf(c4.w, hh.f * __builtin_amdgcn_rcpf(q3), a3);
    }

    sm.b.part[w][0][lane] = a0;
    sm.b.part[w][1][lane] = a1;
    sm.b.part[w][2][lane] = a2;
    sm.b.part[w][3][lane] = a3;
    __syncthreads();

    float acc = sm.b.part[0][w][lane] + sm.b.part[1][w][lane]
              + sm.b.part[2][w][lane] + sm.b.part[3][w][lane];

    float s1 = wave_sum(acc);
    float s2 = wave_sum(acc*acc);
    float mu  = s1 * (1.f/NF);
    float var = s2 * (1.f/NF) - mu*mu;
    float rs  = __builtin_amdgcn_rsqf(var + LN_EPS);
    float o = (acc - mu)*rs*lng[lane] + lnb[lane];
    out[(b*NN + i)*NF + lane] = o;
  }
}

extern "C" void kernel_launch(void* const* d_in, const int* in_sizes, int n_in,
                              void* d_out, int out_size, void* d_ws, size_t ws_size,
                              hipStream_t stream)
{
  const float* x    = (const float*)d_in[0];
  const float* adj  = (const float*)d_in[1];
  const float* Ww   = (const float*)d_in[2];
  const float* Wb   = (const float*)d_in[3];
  const float* Uw   = (const float*)d_in[4];
  const float* Ub   = (const float*)d_in[5];
  const float* Vw   = (const float*)d_in[6];
  const float* Vb   = (const float*)d_in[7];
  const float* attw = (const float*)d_in[8];
  const float* attb = (const float*)d_in[9];
  const float* lng  = (const float*)d_in[10];
  const float* lnb  = (const float*)d_in[11];
  float* ws   = (float*)d_ws;
  float* outp = (float*)d_out;

  void* args[14] = { &x, &adj, &Ww, &Wb, &Uw, &Ub, &Vw, &Vb,
                     &attw, &attb, &lng, &lnb, &ws, &outp };
  hipLaunchCooperativeKernel((const void*)k_fused, dim3(NN), dim3(256),
                             args, 0, stream);
}

// Round 7
// 94.294 us; speedup vs baseline: 1.7398x; 1.7398x over previous
//
#include <hip/hip_runtime.h>

#define NB 4
#define NN 512
#define NF 64
#define NEG_SLOPE 0.2f
#define LN_EPS 1e-5f
#define WP 66   // padded LDS row stride (words): bank = (2*lane + c) % 32 -> 2-way only

__device__ __forceinline__ float wave_sum(float v){
  #pragma unroll
  for (int d = 32; d; d >>= 1) v += __shfl_xor(v, d, 64);
  return v;
}
__device__ __forceinline__ float wave_max(float v){
  #pragma unroll
  for (int d = 32; d; d >>= 1) v = fmaxf(v, __shfl_xor(v, d, 64));
  return v;
}
__device__ __forceinline__ unsigned int rnd_bf_hi(float f){
  union { float f; unsigned int i; } v; v.f = f;
  return (v.i + 0x7fffu + ((v.i >> 16) & 1u)) & 0xffff0000u;
}

// ws layout (words):
//   r   [NN]              adj row-sums (f32)
//   evh [NB*NN*NF]        packed uint32: hi16 = bf16(h), lo16 = bf16(exp(-Vh))
//   eU  [NB*NN*NF]        exp(-Uh) (f32)
//   li  [NB*NN]           h . a_i
//   lj  [NB*NN]           h . a_j

// 512 blocks x 256 threads. Block g: rows g*4+w (w = wave), adj row-sum j = g.
// Weights staged to LDS coalesced once per block; GEMVs read LDS only.
extern "C" __global__ __launch_bounds__(256, 2)
void k_setup(const float* __restrict__ x, const float* __restrict__ adj,
             const float* __restrict__ Ww, const float* __restrict__ Wb,
             const float* __restrict__ Uw, const float* __restrict__ Ub,
             const float* __restrict__ Vw, const float* __restrict__ Vb,
             const float* __restrict__ attw,
             float* __restrict__ ws)
{
  float* r            = ws;
  unsigned int* evh   = (unsigned int*)(ws + NN);
  float* eU           = ws + NN + NB*NN*NF;
  float* li           = eU + NB*NN*NF;
  float* lj           = li + NB*NN;

  __shared__ float s_w[3*64*WP];   // W, U, V padded [f][c]
  __shared__ float s_x[4][NF];
  __shared__ float s_h[4][NF];
  __shared__ float s_red[4];

  const int tid  = threadIdx.x;
  const int w    = tid >> 6;
  const int lane = tid & 63;       // = output feature f
  const int g    = blockIdx.x;
  const int row  = g*4 + w;        // b*NN + n

  // --- stage weights coalesced: 3 x 4096 floats as float4 ---
  {
    const float4* srcs[3] = { (const float4*)Ww, (const float4*)Uw, (const float4*)Vw };
    #pragma unroll
    for (int m = 0; m < 3; m++){
      const float4* src = srcs[m];
      #pragma unroll
      for (int k = 0; k < 4; k++){
        int idx4 = tid + k*256;          // 1024 float4 per matrix
        float4 v = src[idx4];
        int e = idx4 * 4;
        int f = e >> 6, c = e & 63;
        float* dst = &s_w[m*64*WP + f*WP + c];
        dst[0] = v.x; dst[1] = v.y; dst[2] = v.z; dst[3] = v.w;
      }
    }
  }
  s_x[w][lane] = x[row*NF + lane];
  __syncthreads();

  // --- h = x @ Ww^T + Wb (lane = f) ---
  float hv = Wb[lane];
  {
    const float* wr = &s_w[0*64*WP + lane*WP];
    #pragma unroll
    for (int c = 0; c < NF; c += 2){
      float2 xb = *(const float2*)&s_x[w][c];   // LDS broadcast
      float2 wv = *(const float2*)&wr[c];       // 2-way aliased (free)
      hv = fmaf(xb.x, wv.x, hv);
      hv = fmaf(xb.y, wv.y, hv);
    }
  }
  s_h[w][lane] = hv;
  __syncthreads();

  // --- Uh, Vh GEMVs ---
  float uh = Ub[lane];
  float vh = Vb[lane];
  {
    const float* ur = &s_w[1*64*WP + lane*WP];
    const float* vr = &s_w[2*64*WP + lane*WP];
    #pragma unroll
    for (int c = 0; c < NF; c += 2){
      float2 hb = *(const float2*)&s_h[w][c];
      float2 uv = *(const float2*)&ur[c];
      float2 vv = *(const float2*)&vr[c];
      uh = fmaf(hb.x, uv.x, uh); uh = fmaf(hb.y, uv.y, uh);
      vh = fmaf(hb.x, vv.x, vh); vh = fmaf(hb.y, vv.y, vh);
    }
  }

  float ev = __expf(-vh);
  float eu = __expf(-uh);
  evh[row*NF + lane] = rnd_bf_hi(hv) | (rnd_bf_hi(ev) >> 16);
  eU[row*NF + lane] = eu;

  float pi = wave_sum(hv * attw[lane]);
  float pj = wave_sum(hv * attw[NF + lane]);
  if (lane == 0){ li[row] = pi; lj[row] = pj; }

  // --- adj row-sum for j = g (coalesced float2, block reduce) ---
  {
    const float2* a2 = (const float2*)(adj + g*NN);
    float2 a = a2[tid];
    float s = wave_sum(a.x + a.y);
    if (lane == 0) s_red[w] = s;
    __syncthreads();
    if (tid == 0) r[g] = s_red[0] + s_red[1] + s_red[2] + s_red[3];
  }
}

// Block = 4 waves = 4 i-rows; wave w computes softmax for i0+w, then all 4 i's
// over j-quarter [w*128, w*128+128). Packed {bf16(h), bf16(eV)} loaded as one
// coalesced dword from L2; c[j][0..3] via one ds_read_b128 broadcast.
// Partials reduced through LDS, then per-wave layernorm.
extern "C" __global__ __launch_bounds__(256)
void k_main(const float* __restrict__ attb_p,
            const float* __restrict__ lng,
            const float* __restrict__ lnb,
            const float* __restrict__ ws,
            float* __restrict__ out)
{
  const float* r          = ws;
  const unsigned int* evh = (const unsigned int*)(ws + NN);
  const float* eU         = ws + NN + NB*NN*NF;
  const float* li         = eU + NB*NN*NF;
  const float* lj         = li + NB*NN;

  __shared__ float s_c[NN][4];          // c[j][i_local]
  __shared__ float s_part[4][4][NF];    // [wave][i_local][f]

  const int tid  = threadIdx.x;
  const int w    = tid >> 6;
  const int lane = tid & 63;            // = feature f
  const int b    = blockIdx.x >> 7;
  const int i0   = (blockIdx.x & 127) * 4;
  const int i    = i0 + w;

  const float attb = attb_p[0];
  const float li_s = li[b*NN + i];

  float lv[8];
  float m = -1e30f;
  #pragma unroll
  for (int t = 0; t < 8; t++){
    int j = lane + 64*t;
    float l = li_s + lj[b*NN + j] + attb;
    l = (l > 0.f) ? l : NEG_SLOPE*l;
    lv[t] = l;
    m = fmaxf(m, l);
  }
  m = wave_max(m);
  float S = 0.f;
  #pragma unroll
  for (int t = 0; t < 8; t++){ lv[t] = __expf(lv[t] - m); S += lv[t]; }
  S = wave_sum(S);
  float inv = __builtin_amdgcn_rcpf(S);
  #pragma unroll
  for (int t = 0; t < 8; t++){
    int j = lane + 64*t;
    s_c[j][w] = lv[t]*inv*r[j];
  }

  const float eu0 = eU[(b*NN + i0 + 0)*NF + lane];
  const float eu1 = eU[(b*NN + i0 + 1)*NF + lane];
  const float eu2 = eU[(b*NN + i0 + 2)*NF + lane];
  const float eu3 = eU[(b*NN + i0 + 3)*NF + lane];

  __syncthreads();

  const unsigned int* evhb = evh + (size_t)(b*NN)*NF;
  float a0 = 0.f, a1 = 0.f, a2 = 0.f, a3 = 0.f;
  const int j0 = w*128;
  #pragma unroll 8
  for (int jj = 0; jj < 128; jj++){
    int j = j0 + jj;
    unsigned int u = evhb[j*NF + lane];         // coalesced dword, L2-resident
    union { unsigned int i; float f; } hh, ee;
    hh.i = u & 0xffff0000u;                     // bf16(h)
    ee.i = u << 16;                             // bf16(eV)
    float4 c4 = *(const float4*)&s_c[j][0];     // LDS broadcast
    float q0 = fmaf(eu0, ee.f, 1.0f);
    float q1 = fmaf(eu1, ee.f, 1.0f);
    float q2 = fmaf(eu2, ee.f, 1.0f);
    float q3 = fmaf(eu3, ee.f, 1.0f);
    a0 = fmaf(c4.x, hh.f * __builtin_amdgcn_rcpf(q0), a0);
    a1 = fmaf(c4.y, hh.f * __builtin_amdgcn_rcpf(q1), a1);
    a2 = fmaf(c4.z, hh.f * __builtin_amdgcn_rcpf(q2), a2);
    a3 = fmaf(c4.w, hh.f * __builtin_amdgcn_rcpf(q3), a3);
  }

  s_part[w][0][lane] = a0;
  s_part[w][1][lane] = a1;
  s_part[w][2][lane] = a2;
  s_part[w][3][lane] = a3;
  __syncthreads();

  float acc = s_part[0][w][lane] + s_part[1][w][lane]
            + s_part[2][w][lane] + s_part[3][w][lane];

  float s1 = wave_sum(acc);
  float s2 = wave_sum(acc*acc);
  float mu  = s1 * (1.f/NF);
  float var = s2 * (1.f/NF) - mu*mu;
  float rs  = __builtin_amdgcn_rsqf(var + LN_EPS);
  float o = (acc - mu)*rs*lng[lane] + lnb[lane];
  out[(b*NN + i)*NF + lane] = o;
}

extern "C" void kernel_launch(void* const* d_in, const int* in_sizes, int n_in,
                              void* d_out, int out_size, void* d_ws, size_t ws_size,
                              hipStream_t stream)
{
  const float* x    = (const float*)d_in[0];
  const float* adj  = (const float*)d_in[1];
  const float* Ww   = (const float*)d_in[2];
  const float* Wb   = (const float*)d_in[3];
  const float* Uw   = (const float*)d_in[4];
  const float* Ub   = (const float*)d_in[5];
  const float* Vw   = (const float*)d_in[6];
  const float* Vb   = (const float*)d_in[7];
  const float* attw = (const float*)d_in[8];
  const float* attb = (const float*)d_in[9];
  const float* lng  = (const float*)d_in[10];
  const float* lnb  = (const float*)d_in[11];
  float* ws = (float*)d_ws;
  float* outp = (float*)d_out;

  hipLaunchKernelGGL(k_setup, dim3(NN), dim3(256), 0, stream,
                     x, adj, Ww, Wb, Uw, Ub, Vw, Vb, attw, ws);
  hipLaunchKernelGGL(k_main, dim3(NB*NN/4), dim3(256), 0, stream,
                     attb, lng, lnb, ws, outp);
}